// Round 13
// baseline (239.477 us; speedup 1.0000x reference)
//
#include <hip/hip_runtime.h>
#include <hip/hip_bf16.h>

// N=50000 nodes, E=200000 directed edges, H=4 heads, D=64, NODE_IN=6, EDGE_IN=4

typedef __attribute__((ext_vector_type(8))) short short8;          // 8 bf16
typedef __attribute__((ext_vector_type(2))) float f32x2;
typedef __attribute__((ext_vector_type(4))) float f32x4;

template <int CTRL>
__device__ __forceinline__ float dpp_add(float x) {
  int t = __builtin_amdgcn_update_dpp(0, __builtin_bit_cast(int, x),
                                      CTRL, 0xF, 0xF, true);
  return x + __builtin_bit_cast(float, t);
}
// sum over each contiguous 16-lane group (DPP row), result in all 16 lanes
__device__ __forceinline__ float sum16(float p) {
  p = dpp_add<0xB1>(p);   // quad_perm [1,0,3,2]  (xor1)
  p = dpp_add<0x4E>(p);   // quad_perm [2,3,0,1]  (xor2)
  p = dpp_add<0x124>(p);  // row_ror:4
  p = dpp_add<0x128>(p);  // row_ror:8
  return p;
}
__device__ __forceinline__ float wave_reduce_sum(float p) {
  p = sum16(p);
  p += __shfl_xor(p, 16);
  p += __shfl_xor(p, 32);
  return p;
}
__device__ __forceinline__ ushort f2b(float x) {  // fp32 -> bf16 RNE
  union { float f; unsigned u; } a; a.f = x;
  unsigned r = a.u + 0x7FFF + ((a.u >> 16) & 1);
  return (ushort)(r >> 16);
}
__device__ __forceinline__ float b2f(ushort u) {
  return __uint_as_float((unsigned)u << 16);
}

// ---------------- node encoder: node0 = relu(relu(x@W1+b1)@W2+b2), bf16 out -
__global__ __launch_bounds__(256) void node_encoder(
    const float* __restrict__ x, const float* __restrict__ w1,
    const float* __restrict__ b1, const float* __restrict__ w2,
    const float* __restrict__ b2, ushort* __restrict__ out, int N)
{
  __shared__ float sW2[64 * 64];
  __shared__ float sH[4][64];
  int tid = threadIdx.x;
  for (int i = tid; i < 64 * 64; i += 256) sW2[i] = w2[i];
  int wave = tid >> 6, lane = tid & 63;
  int n = blockIdx.x * 4 + wave;
  int nc = n < N ? n : (N - 1);
  float h = b1[lane];
  #pragma unroll
  for (int i = 0; i < 6; ++i) h += x[nc * 6 + i] * w1[i * 64 + lane];
  h = fmaxf(h, 0.f);
  sH[wave][lane] = h;
  __syncthreads();
  float o = b2[lane];
  #pragma unroll 8
  for (int j = 0; j < 64; ++j) o += sH[wave][j] * sW2[j * 64 + lane];
  o = fmaxf(o, 0.f);
  if (n < N) out[n * 64 + lane] = f2b(o);
}

// ------------- weight prep + degree count -----------------------------------
// q-scale (1/8)*log2(e) folded into Wq/bq so attention uses bare exp2f.
__global__ __launch_bounds__(256) void prep_weights(
    const float* __restrict__ tq_w, const float* __restrict__ tk_w,
    const float* __restrict__ tv_w, const float* __restrict__ ts_w,
    const float* __restrict__ tq_b, const float* __restrict__ tk_b,
    const float* __restrict__ tv_b, const float* __restrict__ ts_b,
    const float* __restrict__ pn_w, const float* __restrict__ ec_w1,
    const float* __restrict__ ee_w2,
    ushort* __restrict__ wqkvsT, float* __restrict__ bqkvs,
    ushort* __restrict__ pnT, ushort* __restrict__ ec1T,
    ushort* __restrict__ ee2T,
    const int* __restrict__ ei, int* __restrict__ deg, int E)
{
  const float QSC = 0.125f * 1.4426950408889634f;
  int idx = blockIdx.x * 256 + threadIdx.x;
  if (idx < E) {                            // degree count (folded in)
    atomicAdd(&deg[ei[idx]], 1);
    atomicAdd(&deg[ei[E + idx]], 1);
  }
  if (idx < 131072) {                       // wqkvsT [1024][128], permuted cols
    int p = idx >> 7, k = idx & 127;
    int g, cc;
    if (p < 256) { g = 0; cc = p; }
    else if (p < 768) {
      int d2 = p - 256; int head = d2 >> 7; int ww = d2 & 127;
      int slot = ww >> 3; int o = ww & 7;
      if (o < 4) { g = 1; cc = head * 64 + slot * 4 + o; }
      else       { g = 2; cc = head * 64 + slot * 4 + o - 4; }
    } else { g = 3; cc = p - 768; }
    const float* w = (g == 0) ? tq_w : (g == 1) ? tk_w : (g == 2) ? tv_w : ts_w;
    float v = w[k * 256 + cc];
    if (g == 0) v *= QSC;
    wqkvsT[idx] = f2b(v);
  } else if (idx < 147456) {                // pnT [64][256]
    int i = idx - 131072; int c = i >> 8, k = i & 255;
    pnT[i] = f2b(pn_w[k * 64 + c]);
  } else if (idx < 155648) {                // ec1T [64][128]
    int i = idx - 147456; int c = i >> 7, k = i & 127;
    ec1T[i] = f2b(ec_w1[k * 64 + c]);
  } else if (idx < 159744) {                // ee2T [64][64]
    int i = idx - 155648; int c = i >> 6, k = i & 63;
    ee2T[i] = f2b(ee_w2[k * 64 + c]);
  } else if (idx < 160768) {                // bqkvs [1024], permuted
    int p = idx - 159744;
    int g, cc;
    if (p < 256) { g = 0; cc = p; }
    else if (p < 768) {
      int d2 = p - 256; int head = d2 >> 7; int ww = d2 & 127;
      int slot = ww >> 3; int o = ww & 7;
      if (o < 4) { g = 1; cc = head * 64 + slot * 4 + o; }
      else       { g = 2; cc = head * 64 + slot * 4 + o - 4; }
    } else { g = 3; cc = p - 768; }
    const float* b = (g == 0) ? tq_b : (g == 1) ? tk_b : (g == 2) ? tv_b : ts_b;
    float v = b[cc];
    if (g == 0) v *= QSC;
    bqkvs[p] = v;
  }
}

// ------------- CSR range allocation -----------------------------------------
__global__ __launch_bounds__(64) void alloc_ranges(
    const int* __restrict__ deg, int* __restrict__ base,
    int* __restrict__ fillcur, int* __restrict__ cursor, int N)
{
  int lane = threadIdx.x;
  int n = blockIdx.x * 64 + lane;
  int d = (n < N) ? deg[n] : 0;
  int s = d;
  #pragma unroll
  for (int o = 1; o < 64; o <<= 1) {
    int t = __shfl_up(s, o);
    if (lane >= o) s += t;
  }
  int tot = __shfl(s, 63);
  int wb = 0;
  if (lane == 63) wb = atomicAdd(cursor, tot);
  wb = __shfl(wb, 63);
  if (n < N) { base[n] = wb + s - d; fillcur[n] = wb + s - d; }
}

// ------------- CSR fill: sender per slot + slot pair per edge ---------------
__global__ __launch_bounds__(256) void csr_fill(
    const int* __restrict__ ei, int* __restrict__ fillcur,
    int* __restrict__ csr_send, int2* __restrict__ slot2, int E)
{
  int e = blockIdx.x * 256 + threadIdx.x;
  if (e >= E) return;
  int a = ei[e], b = ei[E + e];
  int pa = atomicAdd(&fillcur[b], 1);   // slot in b's segment, sender a
  csr_send[pa] = a;
  int pb = atomicAdd(&fillcur[a], 1);   // slot in a's segment, sender b
  csr_send[pb] = b;
  slot2[e] = make_int2(pa, pb);
}

// ------------- edge encoder: MLP l1 + MFMA l2, scatter rows to CSR slots ----
__global__ __launch_bounds__(256) void edge_enc(
    const float* __restrict__ ea, const float* __restrict__ w1,
    const float* __restrict__ b1, const ushort* __restrict__ ee2T,
    const float* __restrict__ b2, const int2* __restrict__ slot2,
    ushort* __restrict__ f_csr, int E)
{
  __shared__ ushort As[64 * 72];
  __shared__ ushort Bs[64 * 72];
  __shared__ ushort fT[64 * 72];
  __shared__ int2 sSlot[64];
  int tid = threadIdx.x;
  int wv = tid >> 6, lane = tid & 63, r16 = lane & 15, g4 = lane >> 4;
  int e0 = blockIdx.x * 64;
  if (tid < 64) {
    int e = e0 + tid;
    if (e < E) sSlot[tid] = slot2[e];
  }
  #pragma unroll
  for (int it = 0; it < 2; ++it) {
    int idx = tid + it * 256;
    int r = idx >> 3, c = idx & 7;
    *(short8*)&Bs[r * 72 + c * 8] = *(const short8*)&ee2T[r * 64 + c * 8];
  }
  {
    int c = tid & 63;
    float w0 = w1[c], w1v = w1[64 + c], w2v = w1[128 + c], w3v = w1[192 + c];
    float bb = b1[c];
    int rbase = tid >> 6;
    #pragma unroll
    for (int i = 0; i < 16; ++i) {
      int r = rbase + i * 4;
      int e = e0 + r; if (e >= E) e = E - 1;
      float4 a = *(const float4*)(ea + (size_t)e * 4);
      float hv = bb + a.x * w0 + a.y * w1v + a.z * w2v + a.w * w3v;
      As[r * 72 + c] = f2b(fmaxf(hv, 0.f));
    }
  }
  __syncthreads();
  f32x4 acc[4] = {};
  #pragma unroll
  for (int kk = 0; kk < 2; ++kk) {
    short8 a = *(const short8*)&As[(wv * 16 + r16) * 72 + kk * 32 + g4 * 8];
    #pragma unroll
    for (int sc = 0; sc < 4; ++sc) {
      short8 b = *(const short8*)&Bs[(sc * 16 + r16) * 72 + kk * 32 + g4 * 8];
      acc[sc] = __builtin_amdgcn_mfma_f32_16x16x32_bf16(a, b, acc[sc], 0, 0, 0);
    }
  }
  #pragma unroll
  for (int sc = 0; sc < 4; ++sc) {
    int c = sc * 16 + r16;
    float bs = b2[c];
    #pragma unroll
    for (int j = 0; j < 4; ++j) {
      int r = wv * 16 + g4 * 4 + j;
      fT[r * 72 + c] = f2b(fmaxf(acc[sc][j] + bs, 0.f));
    }
  }
  __syncthreads();
  int gsub = lane >> 4, l16 = lane & 15;
  #pragma unroll
  for (int rr = 0; rr < 8; ++rr) {
    int r = wv * 16 + rr * 2 + (gsub >> 1);
    int e = e0 + r;
    if (e < E) {
      int slot = (gsub & 1) ? sSlot[r].y : sSlot[r].x;
      *(ushort4*)&f_csr[(size_t)slot * 64 + l16 * 4] =
          *(const ushort4*)&fT[r * 72 + l16 * 4];
    }
  }
}

// ------------- agg (contiguous CSR slab) + comb LN (bf16 out) ---------------
__global__ __launch_bounds__(256) void comb_gather_ln(
    const ushort* __restrict__ node, const ushort* __restrict__ f_csr,
    const int* __restrict__ base, const int* __restrict__ deg,
    const float* __restrict__ g, const float* __restrict__ b,
    ushort* __restrict__ comb, int N)
{
  int tid = blockIdx.x * 256 + threadIdx.x;
  int n = tid >> 6, lane = tid & 63;
  if (n >= N) return;
  float v0 = b2f(node[(size_t)n * 64 + lane]);
  float a = 0.f;
  // n is wave-uniform -> force scalar so index math goes to SALU / s_load
  int b0 = __builtin_amdgcn_readfirstlane(base[n]);
  int dn = __builtin_amdgcn_readfirstlane(deg[n]);
  const ushort* fp = f_csr + (size_t)b0 * 64 + lane;
  for (int j = 0; j < dn; j += 4) {
    int o1 = (j + 1 < dn ? j + 1 : j) * 64;
    int o2 = (j + 2 < dn ? j + 2 : j) * 64;
    int o3 = (j + 3 < dn ? j + 3 : j) * 64;
    float f0 = b2f(fp[j * 64]);
    float f1 = b2f(fp[o1]);
    float f2 = b2f(fp[o2]);
    float f3 = b2f(fp[o3]);
    a += f0;
    if (j + 1 < dn) a += f1;
    if (j + 2 < dn) a += f2;
    if (j + 3 < dn) a += f3;
  }
  float v1 = a - v0;
  float s = wave_reduce_sum(v0 + v1);
  float ss = wave_reduce_sum(v0 * v0 + v1 * v1);
  float mean = s * (1.f / 128.f);
  float var = ss * (1.f / 128.f) - mean * mean;
  float rstd = rsqrtf(var + 1e-5f);
  comb[(size_t)n * 128 + lane]      = f2b((v0 - mean) * rstd * g[lane] + b[lane]);
  comb[(size_t)n * 128 + 64 + lane] = f2b((v1 - mean) * rstd * g[64 + lane] + b[64 + lane]);
}

// ------------- fused QKVS GEMM: grid.y=4, 4 col tiles per block -------------
// by=0: q tiles (0-3, bf16) | by=1,2: kv tiles (4-11, fp8) | by=3: s (12-15)
__global__ __launch_bounds__(256) void qkvs_gemm(
    const ushort* __restrict__ comb, const ushort* __restrict__ wqkvsT,
    const float* __restrict__ bias, ushort* __restrict__ qbuf,
    unsigned char* __restrict__ kv8, ushort* __restrict__ sbuf, int N)
{
  __shared__ ushort As[64 * 136];
  __shared__ ushort Bs[64 * 136];
  __shared__ ushort Os[64 * 68];      // bf16 staging; fp8 path aliases as bytes
  int tid = threadIdx.x;
  int wv = tid >> 6, lane = tid & 63, r16 = lane & 15, g4 = lane >> 4;
  int row0 = blockIdx.x * 64;
  int ct0 = blockIdx.y * 4;
  #pragma unroll
  for (int it = 0; it < 4; ++it) {
    int idx = tid + it * 256;
    int r = idx >> 4, c = idx & 15;
    int gr = row0 + r; if (gr >= N) gr = N - 1;
    *(short8*)&As[r * 136 + c * 8] = *(const short8*)&comb[(size_t)gr * 128 + c * 8];
    *(short8*)&Bs[r * 136 + c * 8] =
        *(const short8*)&wqkvsT[(size_t)(ct0 * 64 + r) * 128 + c * 8];
  }
  __syncthreads();
  for (int i = 0; i < 4; ++i) {
    int ct = ct0 + i;
    short8 pf[4];
    if (i < 3) {
      #pragma unroll
      for (int it = 0; it < 4; ++it) {
        int idx = tid + it * 256;
        int r = idx >> 4, c = idx & 15;
        pf[it] = *(const short8*)&wqkvsT[(size_t)((ct + 1) * 64 + r) * 128 + c * 8];
      }
    }
    f32x4 acc[4] = {};
    #pragma unroll
    for (int kk = 0; kk < 4; ++kk) {
      short8 a = *(const short8*)&As[(wv * 16 + r16) * 136 + kk * 32 + g4 * 8];
      #pragma unroll
      for (int sc = 0; sc < 4; ++sc) {
        short8 b = *(const short8*)&Bs[(sc * 16 + r16) * 136 + kk * 32 + g4 * 8];
        acc[sc] = __builtin_amdgcn_mfma_f32_16x16x32_bf16(a, b, acc[sc], 0, 0, 0);
      }
    }
    __syncthreads();   // Bs consumed; previous tile's Os copy-out complete
    if (i < 3) {
      #pragma unroll
      for (int it = 0; it < 4; ++it) {
        int idx = tid + it * 256;
        int r = idx >> 4, c = idx & 15;
        *(short8*)&Bs[r * 136 + c * 8] = pf[it];
      }
    }
    bool isKV = (ct >= 4 && ct < 12);
    if (isKV) {
      unsigned char* Os8 = (unsigned char*)Os;   // [64][80] bytes
      #pragma unroll
      for (int sc = 0; sc < 4; ++sc) {
        float bs = bias[ct * 64 + sc * 16 + r16];
        #pragma unroll
        for (int j = 0; j < 4; ++j) {
          float vv = acc[sc][j] + bs;
          int pk = __builtin_amdgcn_cvt_pk_fp8_f32(vv, vv, 0, false);
          Os8[(wv * 16 + g4 * 4 + j) * 80 + sc * 16 + r16] = (unsigned char)pk;
        }
      }
    } else {
      #pragma unroll
      for (int sc = 0; sc < 4; ++sc) {
        float bs = bias[ct * 64 + sc * 16 + r16];
        #pragma unroll
        for (int j = 0; j < 4; ++j)
          Os[(wv * 16 + g4 * 4 + j) * 68 + sc * 16 + r16] = f2b(acc[sc][j] + bs);
      }
    }
    __syncthreads();   // Os filled, Bs refilled
    if (isKV) {
      const unsigned char* Os8 = (const unsigned char*)Os;
      int r = tid >> 2, ch = tid & 3;            // 64 rows x 4 chunks of 16B
      int gr = row0 + r;
      if (gr < N)
        *(short8*)&kv8[(size_t)gr * 512 + (ct - 4) * 64 + ch * 16] =
            *(const short8*)&Os8[r * 80 + ch * 16];
    } else {
      ushort* dst = (ct < 4) ? qbuf : sbuf;
      int cb = (ct < 4) ? ct : ct - 12;
      #pragma unroll
      for (int it = 0; it < 2; ++it) {
        int idx = tid + it * 256;
        int r = idx >> 3, ch = idx & 7;
        int gr = row0 + r;
        if (gr < N)
          *(short8*)&dst[(size_t)gr * 256 + cb * 64 + ch * 8] =
              *(const short8*)&Os[r * 68 + ch * 8];
      }
    }
  }
}

// ------------- generic bf16 MFMA GEMM (proj) with staged bf16 stores --------
__global__ __launch_bounds__(256) void mgemm(
    const ushort* __restrict__ A, int lda, int M,
    const ushort* __restrict__ BT, const float* __restrict__ bias, int K,
    ushort* __restrict__ outB, int ldo,
    const ushort* __restrict__ res, int ldres, int doRelu)
{
  __shared__ ushort As[64 * 136];
  __shared__ ushort Bs[64 * 136];
  __shared__ ushort Os[64 * 68];
  int tid = threadIdx.x;
  int wv = tid >> 6, lane = tid & 63;
  int r16 = lane & 15, g4 = lane >> 4;
  int row0 = blockIdx.x * 64, col0 = blockIdx.y * 64;
  f32x4 acc[4] = {};
  for (int k0 = 0; k0 < K; k0 += 128) {
    int BK = K - k0; if (BK > 128) BK = 128;
    int csh = (BK == 64) ? 3 : 4;
    int cmask = (1 << csh) - 1;
    int tot = 64 << csh;
    for (int idx = tid; idx < tot; idx += 256) {
      int r = idx >> csh, c = idx & cmask;
      int gr = row0 + r; if (gr >= M) gr = M - 1;
      *(short8*)&As[r * 136 + c * 8] =
          *(const short8*)&A[(size_t)gr * lda + k0 + c * 8];
      *(short8*)&Bs[r * 136 + c * 8] =
          *(const short8*)&BT[(size_t)(col0 + r) * K + k0 + c * 8];
    }
    __syncthreads();
    int ks = BK >> 5;
    for (int kk = 0; kk < ks; ++kk) {
      short8 a = *(const short8*)&As[(wv * 16 + r16) * 136 + kk * 32 + g4 * 8];
      #pragma unroll
      for (int ct = 0; ct < 4; ++ct) {
        short8 b = *(const short8*)&Bs[(ct * 16 + r16) * 136 + kk * 32 + g4 * 8];
        acc[ct] = __builtin_amdgcn_mfma_f32_16x16x32_bf16(a, b, acc[ct], 0, 0, 0);
      }
    }
    __syncthreads();
  }
  #pragma unroll
  for (int ct = 0; ct < 4; ++ct) {
    int c = col0 + ct * 16 + r16;
    float bs = bias[c];
    #pragma unroll
    for (int j = 0; j < 4; ++j) {
      int r = row0 + wv * 16 + g4 * 4 + j;
      int rc = r < M ? r : M - 1;
      float vv = acc[ct][j] + bs;
      if (doRelu) vv = fmaxf(vv, 0.f);
      if (res) vv += b2f(res[(size_t)rc * ldres + c]);
      Os[(wv * 16 + g4 * 4 + j) * 68 + ct * 16 + r16] = f2b(vv);
    }
  }
  __syncthreads();
  #pragma unroll
  for (int it = 0; it < 2; ++it) {
    int idx = tid + it * 256;
    int r = idx >> 3, ch = idx & 7;
    int gr = row0 + r;
    if (gr < M)
      *(short8*)&outB[(size_t)gr * ldo + col0 + ch * 8] =
          *(const short8*)&Os[r * 68 + ch * 8];
  }
}

// ------------- attention + skip + LN; fp8 kv, scalarized indices ------------
__global__ __launch_bounds__(256) void attn_ln2(
    ushort* __restrict__ qbuf, const unsigned char* __restrict__ kv8,
    const ushort* __restrict__ sbuf, const int* __restrict__ base,
    const int* __restrict__ deg, const int* __restrict__ csr_send,
    const float* __restrict__ g, const float* __restrict__ bb, int N)
{
  int tid = blockIdx.x * 256 + threadIdx.x;
  int n = tid >> 6, lane = tid & 63;
  if (n >= N) return;
  int dbase = (lane >> 4) * 64 + (lane & 15) * 4;         // head*64 + slot
  int kvoff = (lane >> 4) * 128 + (lane & 15) * 8;        // fp8 byte offset
  ushort4 qu = *(const ushort4*)(qbuf + (size_t)n * 256 + dbase);
  float q0 = b2f(qu.x), q1 = b2f(qu.y), q2 = b2f(qu.z), q3 = b2f(qu.w);
  float l = 0.f, a0 = 0.f, a1 = 0.f, a2 = 0.f, a3 = 0.f;
  // n is wave-uniform -> force scalar: index math on SALU, csr_send via s_load,
  // kv gathers become saddr-form (scalar base + per-lane kvoff).
  int b0 = __builtin_amdgcn_readfirstlane(base[n]);
  int dn = __builtin_amdgcn_readfirstlane(deg[n]);
  for (int j = 0; j < dn; j += 4) {
    int j1 = (j + 1 < dn ? j + 1 : j);
    int j2 = (j + 2 < dn ? j + 2 : j);
    int j3 = (j + 3 < dn ? j + 3 : j);
    int s0 = __builtin_amdgcn_readfirstlane(csr_send[b0 + j]);
    int s1 = __builtin_amdgcn_readfirstlane(csr_send[b0 + j1]);
    int s2 = __builtin_amdgcn_readfirstlane(csr_send[b0 + j2]);
    int s3 = __builtin_amdgcn_readfirstlane(csr_send[b0 + j3]);
    uint2 kv0 = *(const uint2*)(kv8 + (size_t)s0 * 512 + kvoff);
    uint2 kv1 = *(const uint2*)(kv8 + (size_t)s1 * 512 + kvoff);
    uint2 kv2 = *(const uint2*)(kv8 + (size_t)s2 * 512 + kvoff);
    uint2 kv3 = *(const uint2*)(kv8 + (size_t)s3 * 512 + kvoff);
    f32x2 kA0 = __builtin_amdgcn_cvt_pk_f32_fp8(kv0.x, false);
    f32x2 kA1 = __builtin_amdgcn_cvt_pk_f32_fp8(kv0.x, true);
    f32x2 kB0 = __builtin_amdgcn_cvt_pk_f32_fp8(kv1.x, false);
    f32x2 kB1 = __builtin_amdgcn_cvt_pk_f32_fp8(kv1.x, true);
    f32x2 kC0 = __builtin_amdgcn_cvt_pk_f32_fp8(kv2.x, false);
    f32x2 kC1 = __builtin_amdgcn_cvt_pk_f32_fp8(kv2.x, true);
    f32x2 kD0 = __builtin_amdgcn_cvt_pk_f32_fp8(kv3.x, false);
    f32x2 kD1 = __builtin_amdgcn_cvt_pk_f32_fp8(kv3.x, true);
    float p0 = q0 * kA0[0] + q1 * kA0[1] + q2 * kA1[0] + q3 * kA1[1];
    float p1 = q0 * kB0[0] + q1 * kB0[1] + q2 * kB1[0] + q3 * kB1[1];
    float p2 = q0 * kC0[0] + q1 * kC0[1] + q2 * kC1[0] + q3 * kC1[1];
    float p3 = q0 * kD0[0] + q1 * kD0[1] + q2 * kD1[0] + q3 * kD1[1];
    p0 = sum16(p0); p1 = sum16(p1); p2 = sum16(p2); p3 = sum16(p3);
    float e0 = exp2f(p0);
    float e1 = (j + 1 < dn) ? exp2f(p1) : 0.f;
    float e2 = (j + 2 < dn) ? exp2f(p2) : 0.f;
    float e3 = (j + 3 < dn) ? exp2f(p3) : 0.f;
    l += e0 + e1 + e2 + e3;
    f32x2 vA0 = __builtin_amdgcn_cvt_pk_f32_fp8(kv0.y, false);
    f32x2 vA1 = __builtin_amdgcn_cvt_pk_f32_fp8(kv0.y, true);
    f32x2 vB0 = __builtin_amdgcn_cvt_pk_f32_fp8(kv1.y, false);
    f32x2 vB1 = __builtin_amdgcn_cvt_pk_f32_fp8(kv1.y, true);
    f32x2 vC0 = __builtin_amdgcn_cvt_pk_f32_fp8(kv2.y, false);
    f32x2 vC1 = __builtin_amdgcn_cvt_pk_f32_fp8(kv2.y, true);
    f32x2 vD0 = __builtin_amdgcn_cvt_pk_f32_fp8(kv3.y, false);
    f32x2 vD1 = __builtin_amdgcn_cvt_pk_f32_fp8(kv3.y, true);
    a0 += e0 * vA0[0] + e1 * vB0[0] + e2 * vC0[0] + e3 * vD0[0];
    a1 += e0 * vA0[1] + e1 * vB0[1] + e2 * vC0[1] + e3 * vD0[1];
    a2 += e0 * vA1[0] + e1 * vB1[0] + e2 * vC1[0] + e3 * vD1[0];
    a3 += e0 * vA1[1] + e1 * vB1[1] + e2 * vC1[1] + e3 * vD1[1];
  }
  ushort4 su = *(const ushort4*)(sbuf + (size_t)n * 256 + dbase);
  float rl = 1.f / (l + 1e-16f);
  float y0 = a0 * rl + b2f(su.x), y1 = a1 * rl + b2f(su.y);
  float y2 = a2 * rl + b2f(su.z), y3 = a3 * rl + b2f(su.w);
  float s1 = wave_reduce_sum(y0 + y1 + y2 + y3);
  float s2 = wave_reduce_sum(y0 * y0 + y1 * y1 + y2 * y2 + y3 * y3);
  float mean = s1 * (1.f / 256.f);
  float var = s2 * (1.f / 256.f) - mean * mean;
  float rstd = rsqrtf(var + 1e-5f);
  ushort4 o;
  o.x = f2b((y0 - mean) * rstd * g[dbase + 0] + bb[dbase + 0]);
  o.y = f2b((y1 - mean) * rstd * g[dbase + 1] + bb[dbase + 1]);
  o.z = f2b((y2 - mean) * rstd * g[dbase + 2] + bb[dbase + 2]);
  o.w = f2b((y3 - mean) * rstd * g[dbase + 3] + bb[dbase + 3]);
  *(ushort4*)(qbuf + (size_t)n * 256 + dbase) = o;   // outn over q
}

// ------------- classifier, fully fused: gather + GEMM + relu + dot(w2) ------
__global__ __launch_bounds__(256) void clf_fused(
    const ushort* __restrict__ nodeB, const int* __restrict__ ei,
    const ushort* __restrict__ ec1T, const float* __restrict__ b1,
    const float* __restrict__ w2, const float* __restrict__ b2v,
    float* __restrict__ out, int E)
{
  __shared__ ushort As[64 * 136];
  __shared__ ushort Bs[64 * 136];
  int tid = threadIdx.x;
  int wv = tid >> 6, lane = tid & 63;
  int r16 = lane & 15, g4 = lane >> 4;
  int e0 = blockIdx.x * 64;
  for (int idx = tid; idx < 1024; idx += 256) {
    int r = idx >> 4, c = idx & 15;
    int e = e0 + r; if (e >= E) e = E - 1;
    int node = (c < 8) ? ei[e] : ei[E + e];
    *(short8*)&As[r * 136 + c * 8] =
        *(const short8*)&nodeB[(size_t)node * 64 + (c & 7) * 8];
    *(short8*)&Bs[r * 136 + c * 8] = *(const short8*)&ec1T[r * 128 + c * 8];
  }
  __syncthreads();
  f32x4 acc[4] = {};
  #pragma unroll
  for (int kk = 0; kk < 4; ++kk) {
    short8 a = *(const short8*)&As[(wv * 16 + r16) * 136 + kk * 32 + g4 * 8];
    #pragma unroll
    for (int ct = 0; ct < 4; ++ct) {
      short8 b = *(const short8*)&Bs[(ct * 16 + r16) * 136 + kk * 32 + g4 * 8];
      acc[ct] = __builtin_amdgcn_mfma_f32_16x16x32_bf16(a, b, acc[ct], 0, 0, 0);
    }
  }
  float p0 = 0.f, p1 = 0.f, p2 = 0.f, p3 = 0.f;
  #pragma unroll
  for (int ct = 0; ct < 4; ++ct) {
    int c = ct * 16 + r16;
    float bb1 = b1[c], ww = w2[c];
    p0 += fmaxf(acc[ct][0] + bb1, 0.f) * ww;
    p1 += fmaxf(acc[ct][1] + bb1, 0.f) * ww;
    p2 += fmaxf(acc[ct][2] + bb1, 0.f) * ww;
    p3 += fmaxf(acc[ct][3] + bb1, 0.f) * ww;
  }
  float part[4] = {p0, p1, p2, p3};
  #pragma unroll
  for (int j = 0; j < 4; ++j) {
    float p = sum16(part[j]);
    int r = e0 + wv * 16 + g4 * 4 + j;
    if (r16 == 0 && r < E) out[r] = p + b2v[0];
  }
}

extern "C" void kernel_launch(void* const* d_in, const int* in_sizes, int n_in,
                              void* d_out, int out_size, void* d_ws, size_t ws_size,
                              hipStream_t stream)
{
  const float* x     = (const float*)d_in[0];
  const float* ea    = (const float*)d_in[1];
  const float* ne_w1 = (const float*)d_in[2];
  const float* ne_b1 = (const float*)d_in[3];
  const float* ne_w2 = (const float*)d_in[4];
  const float* ne_b2 = (const float*)d_in[5];
  const float* ee_w1 = (const float*)d_in[6];
  const float* ee_b1 = (const float*)d_in[7];
  const float* ee_w2 = (const float*)d_in[8];
  const float* ee_b2 = (const float*)d_in[9];
  const float* lnc_g = (const float*)d_in[10];
  const float* lnc_b = (const float*)d_in[11];
  const float* tq_w  = (const float*)d_in[12];
  const float* tq_b  = (const float*)d_in[13];
  const float* tk_w  = (const float*)d_in[14];
  const float* tk_b  = (const float*)d_in[15];
  const float* tv_w  = (const float*)d_in[16];
  const float* tv_b  = (const float*)d_in[17];
  const float* ts_w  = (const float*)d_in[18];
  const float* ts_b  = (const float*)d_in[19];
  const float* lnt_g = (const float*)d_in[20];
  const float* lnt_b = (const float*)d_in[21];
  const float* pn_w  = (const float*)d_in[22];
  const float* pn_b  = (const float*)d_in[23];
  // d_in[24], d_in[25] = pe_w, pe_b : dead code (n_iterations=1)
  const float* ec_w1 = (const float*)d_in[26];
  const float* ec_b1 = (const float*)d_in[27];
  const float* ec_w2 = (const float*)d_in[28];
  const float* ec_b2 = (const float*)d_in[29];
  const int*   ei    = (const int*)d_in[30];

  const int N = in_sizes[0] / 6;
  const int E = in_sizes[1] / 4;
  float* out = (float*)d_out;

  char* w = (char*)d_ws;
  size_t off = 0;
  auto alloc = [&](size_t bytes) -> char* {
    char* p = w + off;
    off = (off + bytes + 255) & ~(size_t)255;
    return p;
  };
  ushort* node0   = (ushort*)alloc((size_t)N * 64 * 2);     // bf16
  ushort* comb    = (ushort*)alloc((size_t)N * 128 * 2);
  ushort* qbuf    = (ushort*)alloc((size_t)N * 256 * 2);    // q, then outn
  unsigned char* kv8 = (unsigned char*)alloc((size_t)N * 512); // fp8 k|v interleaved
  ushort* sbuf    = (ushort*)alloc((size_t)N * 256 * 2);
  ushort* f_csr   = (ushort*)alloc((size_t)2 * E * 64 * 2); // edge feats, slot order
  ushort* nodeB   = (ushort*)alloc((size_t)N * 64 * 2);
  ushort* wqkvsT  = (ushort*)alloc(1024 * 128 * 2);
  float*  bqkvs   = (float*)alloc(1024 * 4);
  ushort* pnT     = (ushort*)alloc(64 * 256 * 2);
  ushort* ec1T    = (ushort*)alloc(64 * 128 * 2);
  ushort* ee2T    = (ushort*)alloc(64 * 64 * 2);
  int* deg      = (int*)alloc((size_t)N * 4);
  int* base     = (int*)alloc((size_t)N * 4);
  int* fillcur  = (int*)alloc((size_t)N * 4);
  int* csr_send = (int*)alloc((size_t)2 * E * 4);
  int2* slot2   = (int2*)alloc((size_t)E * 8);
  int* cursor   = (int*)alloc(256);

  hipMemsetAsync(deg, 0, (size_t)N * 4, stream);
  hipMemsetAsync(cursor, 0, 4, stream);

  // weight prep (transpose + bf16 + kv-permute + q-scale) + degree count
  int prep_n = (E > 160768) ? E : 160768;
  prep_weights<<<(prep_n + 255) / 256, 256, 0, stream>>>(
      tq_w, tk_w, tv_w, ts_w, tq_b, tk_b, tv_b, ts_b, pn_w, ec_w1, ee_w2,
      wqkvsT, bqkvs, pnT, ec1T, ee2T, ei, deg, E);
  // node encoder (fp32 compute, bf16 out)
  node_encoder<<<(N + 3) / 4, 256, 0, stream>>>(x, ne_w1, ne_b1, ne_w2, ne_b2, node0, N);
  // CSR ranges -> slot assignment
  alloc_ranges<<<(N + 63) / 64, 64, 0, stream>>>(deg, base, fillcur, cursor, N);
  csr_fill<<<(E + 255) / 256, 256, 0, stream>>>(ei, fillcur, csr_send, slot2, E);
  // edge encoder -> f_csr (scatter to both slots; agg reads become streaming)
  edge_enc<<<(E + 63) / 64, 256, 0, stream>>>(ea, ee_w1, ee_b1, ee2T, ee_b2,
                                              slot2, f_csr, E);
  // agg (contiguous slab) + comb LN -> bf16
  comb_gather_ln<<<(N * 64 + 255) / 256, 256, 0, stream>>>(
      node0, f_csr, base, deg, lnc_g, lnc_b, comb, N);
  // fused QKVS projection: q/s bf16, kv fp8; col tiles split over grid.y
  qkvs_gemm<<<dim3((N + 63) / 64, 4), 256, 0, stream>>>(
      comb, wqkvsT, bqkvs, qbuf, kv8, sbuf, N);
  // attention + skip + LN (outn over qbuf)
  attn_ln2<<<(N * 64 + 255) / 256, 256, 0, stream>>>(
      qbuf, kv8, sbuf, base, deg, csr_send, lnt_g, lnt_b, N);
  // node projection + residual -> nodeB
  mgemm<<<dim3((N + 63) / 64, 1), 256, 0, stream>>>(
      qbuf, 256, N, pnT, pn_b, 256, nodeB, 64, node0, 64, 0);
  // classifier: gather + GEMM + relu + dot(w2) fused
  clf_fused<<<(E + 63) / 64, 256, 0, stream>>>(
      nodeB, ei, ec1T, ec_b1, ec_w2, ec_b2, out, E);
}

// Round 14
// 238.464 us; speedup vs baseline: 1.0042x; 1.0042x over previous
//
#include <hip/hip_runtime.h>
#include <hip/hip_bf16.h>

// N=50000 nodes, E=200000 directed edges, H=4 heads, D=64, NODE_IN=6, EDGE_IN=4

typedef __attribute__((ext_vector_type(8))) short short8;          // 8 bf16
typedef __attribute__((ext_vector_type(2))) float f32x2;
typedef __attribute__((ext_vector_type(4))) float f32x4;

template <int CTRL>
__device__ __forceinline__ float dpp_add(float x) {
  int t = __builtin_amdgcn_update_dpp(0, __builtin_bit_cast(int, x),
                                      CTRL, 0xF, 0xF, true);
  return x + __builtin_bit_cast(float, t);
}
// sum over each contiguous 16-lane group (DPP row), result in all 16 lanes
__device__ __forceinline__ float sum16(float p) {
  p = dpp_add<0xB1>(p);   // quad_perm [1,0,3,2]  (xor1)
  p = dpp_add<0x4E>(p);   // quad_perm [2,3,0,1]  (xor2)
  p = dpp_add<0x124>(p);  // row_ror:4
  p = dpp_add<0x128>(p);  // row_ror:8
  return p;
}
__device__ __forceinline__ float wave_reduce_sum(float p) {
  p = sum16(p);
  p += __shfl_xor(p, 16);
  p += __shfl_xor(p, 32);
  return p;
}
__device__ __forceinline__ ushort f2b(float x) {  // fp32 -> bf16 RNE
  union { float f; unsigned u; } a; a.f = x;
  unsigned r = a.u + 0x7FFF + ((a.u >> 16) & 1);
  return (ushort)(r >> 16);
}
__device__ __forceinline__ float b2f(ushort u) {
  return __uint_as_float((unsigned)u << 16);
}

// ---------------- node encoder: node0 = relu(relu(x@W1+b1)@W2+b2), bf16 out -
__global__ __launch_bounds__(256) void node_encoder(
    const float* __restrict__ x, const float* __restrict__ w1,
    const float* __restrict__ b1, const float* __restrict__ w2,
    const float* __restrict__ b2, ushort* __restrict__ out, int N)
{
  __shared__ float sW2[64 * 64];
  __shared__ float sH[4][64];
  int tid = threadIdx.x;
  for (int i = tid; i < 64 * 64; i += 256) sW2[i] = w2[i];
  int wave = tid >> 6, lane = tid & 63;
  int n = blockIdx.x * 4 + wave;
  int nc = n < N ? n : (N - 1);
  float h = b1[lane];
  #pragma unroll
  for (int i = 0; i < 6; ++i) h += x[nc * 6 + i] * w1[i * 64 + lane];
  h = fmaxf(h, 0.f);
  sH[wave][lane] = h;
  __syncthreads();
  float o = b2[lane];
  #pragma unroll 8
  for (int j = 0; j < 64; ++j) o += sH[wave][j] * sW2[j * 64 + lane];
  o = fmaxf(o, 0.f);
  if (n < N) out[n * 64 + lane] = f2b(o);
}

// ------------- weight prep + degree count -----------------------------------
// q-scale (1/8)*log2(e) folded into Wq/bq so attention uses bare exp2f.
__global__ __launch_bounds__(256) void prep_weights(
    const float* __restrict__ tq_w, const float* __restrict__ tk_w,
    const float* __restrict__ tv_w, const float* __restrict__ ts_w,
    const float* __restrict__ tq_b, const float* __restrict__ tk_b,
    const float* __restrict__ tv_b, const float* __restrict__ ts_b,
    const float* __restrict__ pn_w, const float* __restrict__ ec_w1,
    const float* __restrict__ ee_w2,
    ushort* __restrict__ wqkvsT, float* __restrict__ bqkvs,
    ushort* __restrict__ pnT, ushort* __restrict__ ec1T,
    ushort* __restrict__ ee2T,
    const int* __restrict__ ei, int* __restrict__ deg, int E)
{
  const float QSC = 0.125f * 1.4426950408889634f;
  int idx = blockIdx.x * 256 + threadIdx.x;
  if (idx < E) {                            // degree count (folded in)
    atomicAdd(&deg[ei[idx]], 1);
    atomicAdd(&deg[ei[E + idx]], 1);
  }
  if (idx < 131072) {                       // wqkvsT [1024][128], permuted cols
    int p = idx >> 7, k = idx & 127;
    int g, cc;
    if (p < 256) { g = 0; cc = p; }
    else if (p < 768) {
      int d2 = p - 256; int head = d2 >> 7; int ww = d2 & 127;
      int slot = ww >> 3; int o = ww & 7;
      if (o < 4) { g = 1; cc = head * 64 + slot * 4 + o; }
      else       { g = 2; cc = head * 64 + slot * 4 + o - 4; }
    } else { g = 3; cc = p - 768; }
    const float* w = (g == 0) ? tq_w : (g == 1) ? tk_w : (g == 2) ? tv_w : ts_w;
    float v = w[k * 256 + cc];
    if (g == 0) v *= QSC;
    wqkvsT[idx] = f2b(v);
  } else if (idx < 147456) {                // pnT [64][256]
    int i = idx - 131072; int c = i >> 8, k = i & 255;
    pnT[i] = f2b(pn_w[k * 64 + c]);
  } else if (idx < 155648) {                // ec1T [64][128]
    int i = idx - 147456; int c = i >> 7, k = i & 127;
    ec1T[i] = f2b(ec_w1[k * 64 + c]);
  } else if (idx < 159744) {                // ee2T [64][64]
    int i = idx - 155648; int c = i >> 6, k = i & 63;
    ee2T[i] = f2b(ee_w2[k * 64 + c]);
  } else if (idx < 160768) {                // bqkvs [1024], permuted
    int p = idx - 159744;
    int g, cc;
    if (p < 256) { g = 0; cc = p; }
    else if (p < 768) {
      int d2 = p - 256; int head = d2 >> 7; int ww = d2 & 127;
      int slot = ww >> 3; int o = ww & 7;
      if (o < 4) { g = 1; cc = head * 64 + slot * 4 + o; }
      else       { g = 2; cc = head * 64 + slot * 4 + o - 4; }
    } else { g = 3; cc = p - 768; }
    const float* b = (g == 0) ? tq_b : (g == 1) ? tk_b : (g == 2) ? tv_b : ts_b;
    float v = b[cc];
    if (g == 0) v *= QSC;
    bqkvs[p] = v;
  }
}

// ------------- CSR range allocation -----------------------------------------
__global__ __launch_bounds__(64) void alloc_ranges(
    const int* __restrict__ deg, int* __restrict__ base,
    int* __restrict__ fillcur, int* __restrict__ cursor, int N)
{
  int lane = threadIdx.x;
  int n = blockIdx.x * 64 + lane;
  int d = (n < N) ? deg[n] : 0;
  int s = d;
  #pragma unroll
  for (int o = 1; o < 64; o <<= 1) {
    int t = __shfl_up(s, o);
    if (lane >= o) s += t;
  }
  int tot = __shfl(s, 63);
  int wb = 0;
  if (lane == 63) wb = atomicAdd(cursor, tot);
  wb = __shfl(wb, 63);
  if (n < N) { base[n] = wb + s - d; fillcur[n] = wb + s - d; }
}

// ------------- CSR fill: sender per slot + slot pair per edge ---------------
__global__ __launch_bounds__(256) void csr_fill(
    const int* __restrict__ ei, int* __restrict__ fillcur,
    int* __restrict__ csr_send, int2* __restrict__ slot2, int E)
{
  int e = blockIdx.x * 256 + threadIdx.x;
  if (e >= E) return;
  int a = ei[e], b = ei[E + e];
  int pa = atomicAdd(&fillcur[b], 1);   // slot in b's segment, sender a
  csr_send[pa] = a;
  int pb = atomicAdd(&fillcur[a], 1);   // slot in a's segment, sender b
  csr_send[pb] = b;
  slot2[e] = make_int2(pa, pb);
}

// ------------- edge encoder: MLP l1 + MFMA l2, scatter rows to CSR slots ----
__global__ __launch_bounds__(256) void edge_enc(
    const float* __restrict__ ea, const float* __restrict__ w1,
    const float* __restrict__ b1, const ushort* __restrict__ ee2T,
    const float* __restrict__ b2, const int2* __restrict__ slot2,
    ushort* __restrict__ f_csr, int E)
{
  __shared__ ushort As[64 * 72];
  __shared__ ushort Bs[64 * 72];
  __shared__ ushort fT[64 * 72];
  __shared__ int2 sSlot[64];
  int tid = threadIdx.x;
  int wv = tid >> 6, lane = tid & 63, r16 = lane & 15, g4 = lane >> 4;
  int e0 = blockIdx.x * 64;
  if (tid < 64) {
    int e = e0 + tid;
    if (e < E) sSlot[tid] = slot2[e];
  }
  #pragma unroll
  for (int it = 0; it < 2; ++it) {
    int idx = tid + it * 256;
    int r = idx >> 3, c = idx & 7;
    *(short8*)&Bs[r * 72 + c * 8] = *(const short8*)&ee2T[r * 64 + c * 8];
  }
  {
    int c = tid & 63;
    float w0 = w1[c], w1v = w1[64 + c], w2v = w1[128 + c], w3v = w1[192 + c];
    float bb = b1[c];
    int rbase = tid >> 6;
    #pragma unroll
    for (int i = 0; i < 16; ++i) {
      int r = rbase + i * 4;
      int e = e0 + r; if (e >= E) e = E - 1;
      float4 a = *(const float4*)(ea + (size_t)e * 4);
      float hv = bb + a.x * w0 + a.y * w1v + a.z * w2v + a.w * w3v;
      As[r * 72 + c] = f2b(fmaxf(hv, 0.f));
    }
  }
  __syncthreads();
  f32x4 acc[4] = {};
  #pragma unroll
  for (int kk = 0; kk < 2; ++kk) {
    short8 a = *(const short8*)&As[(wv * 16 + r16) * 72 + kk * 32 + g4 * 8];
    #pragma unroll
    for (int sc = 0; sc < 4; ++sc) {
      short8 b = *(const short8*)&Bs[(sc * 16 + r16) * 72 + kk * 32 + g4 * 8];
      acc[sc] = __builtin_amdgcn_mfma_f32_16x16x32_bf16(a, b, acc[sc], 0, 0, 0);
    }
  }
  #pragma unroll
  for (int sc = 0; sc < 4; ++sc) {
    int c = sc * 16 + r16;
    float bs = b2[c];
    #pragma unroll
    for (int j = 0; j < 4; ++j) {
      int r = wv * 16 + g4 * 4 + j;
      fT[r * 72 + c] = f2b(fmaxf(acc[sc][j] + bs, 0.f));
    }
  }
  __syncthreads();
  int gsub = lane >> 4, l16 = lane & 15;
  #pragma unroll
  for (int rr = 0; rr < 8; ++rr) {
    int r = wv * 16 + rr * 2 + (gsub >> 1);
    int e = e0 + r;
    if (e < E) {
      int slot = (gsub & 1) ? sSlot[r].y : sSlot[r].x;
      *(ushort4*)&f_csr[(size_t)slot * 64 + l16 * 4] =
          *(const ushort4*)&fT[r * 72 + l16 * 4];
    }
  }
}

// ------------- agg (contiguous CSR slab) + comb LN (bf16 out) ---------------
__global__ __launch_bounds__(256) void comb_gather_ln(
    const ushort* __restrict__ node, const ushort* __restrict__ f_csr,
    const int* __restrict__ base, const int* __restrict__ deg,
    const float* __restrict__ g, const float* __restrict__ b,
    ushort* __restrict__ comb, int N)
{
  int tid = blockIdx.x * 256 + threadIdx.x;
  int n = tid >> 6, lane = tid & 63;
  if (n >= N) return;
  float v0 = b2f(node[(size_t)n * 64 + lane]);
  float a = 0.f;
  int b0 = __builtin_amdgcn_readfirstlane(base[n]);
  int dn = __builtin_amdgcn_readfirstlane(deg[n]);
  const ushort* fp = f_csr + (size_t)b0 * 64 + lane;
  for (int j = 0; j < dn; j += 4) {
    int o1 = (j + 1 < dn ? j + 1 : j) * 64;
    int o2 = (j + 2 < dn ? j + 2 : j) * 64;
    int o3 = (j + 3 < dn ? j + 3 : j) * 64;
    float f0 = b2f(fp[j * 64]);
    float f1 = b2f(fp[o1]);
    float f2 = b2f(fp[o2]);
    float f3 = b2f(fp[o3]);
    a += f0;
    if (j + 1 < dn) a += f1;
    if (j + 2 < dn) a += f2;
    if (j + 3 < dn) a += f3;
  }
  float v1 = a - v0;
  float s = wave_reduce_sum(v0 + v1);
  float ss = wave_reduce_sum(v0 * v0 + v1 * v1);
  float mean = s * (1.f / 128.f);
  float var = ss * (1.f / 128.f) - mean * mean;
  float rstd = rsqrtf(var + 1e-5f);
  comb[(size_t)n * 128 + lane]      = f2b((v0 - mean) * rstd * g[lane] + b[lane]);
  comb[(size_t)n * 128 + 64 + lane] = f2b((v1 - mean) * rstd * g[64 + lane] + b[64 + lane]);
}

// ------------- fused QKVS GEMM: grid.y=4, 4 col tiles per block -------------
// by=0: q tiles (0-3, bf16) | by=1,2: kv tiles (4-11, fp8) | by=3: s (12-15)
__global__ __launch_bounds__(256) void qkvs_gemm(
    const ushort* __restrict__ comb, const ushort* __restrict__ wqkvsT,
    const float* __restrict__ bias, ushort* __restrict__ qbuf,
    unsigned char* __restrict__ kv8, ushort* __restrict__ sbuf, int N)
{
  __shared__ ushort As[64 * 136];
  __shared__ ushort Bs[64 * 136];
  __shared__ ushort Os[64 * 68];      // bf16 staging; fp8 path aliases as bytes
  int tid = threadIdx.x;
  int wv = tid >> 6, lane = tid & 63, r16 = lane & 15, g4 = lane >> 4;
  int row0 = blockIdx.x * 64;
  int ct0 = blockIdx.y * 4;
  #pragma unroll
  for (int it = 0; it < 4; ++it) {
    int idx = tid + it * 256;
    int r = idx >> 4, c = idx & 15;
    int gr = row0 + r; if (gr >= N) gr = N - 1;
    *(short8*)&As[r * 136 + c * 8] = *(const short8*)&comb[(size_t)gr * 128 + c * 8];
    *(short8*)&Bs[r * 136 + c * 8] =
        *(const short8*)&wqkvsT[(size_t)(ct0 * 64 + r) * 128 + c * 8];
  }
  __syncthreads();
  for (int i = 0; i < 4; ++i) {
    int ct = ct0 + i;
    short8 pf[4];
    if (i < 3) {
      #pragma unroll
      for (int it = 0; it < 4; ++it) {
        int idx = tid + it * 256;
        int r = idx >> 4, c = idx & 15;
        pf[it] = *(const short8*)&wqkvsT[(size_t)((ct + 1) * 64 + r) * 128 + c * 8];
      }
    }
    f32x4 acc[4] = {};
    #pragma unroll
    for (int kk = 0; kk < 4; ++kk) {
      short8 a = *(const short8*)&As[(wv * 16 + r16) * 136 + kk * 32 + g4 * 8];
      #pragma unroll
      for (int sc = 0; sc < 4; ++sc) {
        short8 b = *(const short8*)&Bs[(sc * 16 + r16) * 136 + kk * 32 + g4 * 8];
        acc[sc] = __builtin_amdgcn_mfma_f32_16x16x32_bf16(a, b, acc[sc], 0, 0, 0);
      }
    }
    __syncthreads();   // Bs consumed; previous tile's Os copy-out complete
    if (i < 3) {
      #pragma unroll
      for (int it = 0; it < 4; ++it) {
        int idx = tid + it * 256;
        int r = idx >> 4, c = idx & 15;
        *(short8*)&Bs[r * 136 + c * 8] = pf[it];
      }
    }
    bool isKV = (ct >= 4 && ct < 12);
    if (isKV) {
      unsigned char* Os8 = (unsigned char*)Os;   // [64][80] bytes
      #pragma unroll
      for (int sc = 0; sc < 4; ++sc) {
        float bs = bias[ct * 64 + sc * 16 + r16];
        #pragma unroll
        for (int j = 0; j < 4; ++j) {
          float vv = acc[sc][j] + bs;
          int pk = __builtin_amdgcn_cvt_pk_fp8_f32(vv, vv, 0, false);
          Os8[(wv * 16 + g4 * 4 + j) * 80 + sc * 16 + r16] = (unsigned char)pk;
        }
      }
    } else {
      #pragma unroll
      for (int sc = 0; sc < 4; ++sc) {
        float bs = bias[ct * 64 + sc * 16 + r16];
        #pragma unroll
        for (int j = 0; j < 4; ++j)
          Os[(wv * 16 + g4 * 4 + j) * 68 + sc * 16 + r16] = f2b(acc[sc][j] + bs);
      }
    }
    __syncthreads();   // Os filled, Bs refilled
    if (isKV) {
      const unsigned char* Os8 = (const unsigned char*)Os;
      int r = tid >> 2, ch = tid & 3;            // 64 rows x 4 chunks of 16B
      int gr = row0 + r;
      if (gr < N)
        *(short8*)&kv8[(size_t)gr * 512 + (ct - 4) * 64 + ch * 16] =
            *(const short8*)&Os8[r * 80 + ch * 16];
    } else {
      ushort* dst = (ct < 4) ? qbuf : sbuf;
      int cb = (ct < 4) ? ct : ct - 12;
      #pragma unroll
      for (int it = 0; it < 2; ++it) {
        int idx = tid + it * 256;
        int r = idx >> 3, ch = idx & 7;
        int gr = row0 + r;
        if (gr < N)
          *(short8*)&dst[(size_t)gr * 256 + cb * 64 + ch * 8] =
              *(const short8*)&Os[r * 68 + ch * 8];
      }
    }
  }
}

// ------------- generic bf16 MFMA GEMM (proj) with staged bf16 stores --------
__global__ __launch_bounds__(256) void mgemm(
    const ushort* __restrict__ A, int lda, int M,
    const ushort* __restrict__ BT, const float* __restrict__ bias, int K,
    ushort* __restrict__ outB, int ldo,
    const ushort* __restrict__ res, int ldres, int doRelu)
{
  __shared__ ushort As[64 * 136];
  __shared__ ushort Bs[64 * 136];
  __shared__ ushort Os[64 * 68];
  int tid = threadIdx.x;
  int wv = tid >> 6, lane = tid & 63;
  int r16 = lane & 15, g4 = lane >> 4;
  int row0 = blockIdx.x * 64, col0 = blockIdx.y * 64;
  f32x4 acc[4] = {};
  for (int k0 = 0; k0 < K; k0 += 128) {
    int BK = K - k0; if (BK > 128) BK = 128;
    int csh = (BK == 64) ? 3 : 4;
    int cmask = (1 << csh) - 1;
    int tot = 64 << csh;
    for (int idx = tid; idx < tot; idx += 256) {
      int r = idx >> csh, c = idx & cmask;
      int gr = row0 + r; if (gr >= M) gr = M - 1;
      *(short8*)&As[r * 136 + c * 8] =
          *(const short8*)&A[(size_t)gr * lda + k0 + c * 8];
      *(short8*)&Bs[r * 136 + c * 8] =
          *(const short8*)&BT[(size_t)(col0 + r) * K + k0 + c * 8];
    }
    __syncthreads();
    int ks = BK >> 5;
    for (int kk = 0; kk < ks; ++kk) {
      short8 a = *(const short8*)&As[(wv * 16 + r16) * 136 + kk * 32 + g4 * 8];
      #pragma unroll
      for (int ct = 0; ct < 4; ++ct) {
        short8 b = *(const short8*)&Bs[(ct * 16 + r16) * 136 + kk * 32 + g4 * 8];
        acc[ct] = __builtin_amdgcn_mfma_f32_16x16x32_bf16(a, b, acc[ct], 0, 0, 0);
      }
    }
    __syncthreads();
  }
  #pragma unroll
  for (int ct = 0; ct < 4; ++ct) {
    int c = col0 + ct * 16 + r16;
    float bs = bias[c];
    #pragma unroll
    for (int j = 0; j < 4; ++j) {
      int r = row0 + wv * 16 + g4 * 4 + j;
      int rc = r < M ? r : M - 1;
      float vv = acc[ct][j] + bs;
      if (doRelu) vv = fmaxf(vv, 0.f);
      if (res) vv += b2f(res[(size_t)rc * ldres + c]);
      Os[(wv * 16 + g4 * 4 + j) * 68 + ct * 16 + r16] = f2b(vv);
    }
  }
  __syncthreads();
  #pragma unroll
  for (int it = 0; it < 2; ++it) {
    int idx = tid + it * 256;
    int r = idx >> 3, ch = idx & 7;
    int gr = row0 + r;
    if (gr < M)
      *(short8*)&outB[(size_t)gr * ldo + col0 + ch * 8] =
          *(const short8*)&Os[r * 68 + ch * 8];
  }
}

// ------------- attention + skip + LN; fp8 kv, software-pipelined gather -----
__global__ __launch_bounds__(256) void attn_ln2(
    ushort* __restrict__ qbuf, const unsigned char* __restrict__ kv8,
    const ushort* __restrict__ sbuf, const int* __restrict__ base,
    const int* __restrict__ deg, const int* __restrict__ csr_send,
    const float* __restrict__ g, const float* __restrict__ bb, int N)
{
  int tid = blockIdx.x * 256 + threadIdx.x;
  int n = tid >> 6, lane = tid & 63;
  if (n >= N) return;
  int dbase = (lane >> 4) * 64 + (lane & 15) * 4;         // head*64 + slot
  int kvoff = (lane >> 4) * 128 + (lane & 15) * 8;        // fp8 byte offset
  ushort4 qu = *(const ushort4*)(qbuf + (size_t)n * 256 + dbase);
  float q0 = b2f(qu.x), q1 = b2f(qu.y), q2 = b2f(qu.z), q3 = b2f(qu.w);
  float l = 0.f, a0 = 0.f, a1 = 0.f, a2 = 0.f, a3 = 0.f;
  int b0 = __builtin_amdgcn_readfirstlane(base[n]);
  int dn = __builtin_amdgcn_readfirstlane(deg[n]);
  // prologue: load batch 0
  uint2 c0, c1, c2, c3;
  {
    int j1 = (1 < dn ? 1 : dn - 1);
    int j2 = (2 < dn ? 2 : dn - 1);
    int j3 = (3 < dn ? 3 : dn - 1);
    int s0 = __builtin_amdgcn_readfirstlane(csr_send[b0]);
    int s1 = __builtin_amdgcn_readfirstlane(csr_send[b0 + j1]);
    int s2 = __builtin_amdgcn_readfirstlane(csr_send[b0 + j2]);
    int s3 = __builtin_amdgcn_readfirstlane(csr_send[b0 + j3]);
    c0 = *(const uint2*)(kv8 + (size_t)s0 * 512 + kvoff);
    c1 = *(const uint2*)(kv8 + (size_t)s1 * 512 + kvoff);
    c2 = *(const uint2*)(kv8 + (size_t)s2 * 512 + kvoff);
    c3 = *(const uint2*)(kv8 + (size_t)s3 * 512 + kvoff);
  }
  for (int j = 0; j < dn; j += 4) {
    // prefetch batch j+4 (clamped; duplicates are L2 hits)
    uint2 n0, n1, n2, n3;
    {
      int j4 = (j + 4 < dn ? j + 4 : dn - 1);
      int j5 = (j + 5 < dn ? j + 5 : dn - 1);
      int j6 = (j + 6 < dn ? j + 6 : dn - 1);
      int j7 = (j + 7 < dn ? j + 7 : dn - 1);
      int s0 = __builtin_amdgcn_readfirstlane(csr_send[b0 + j4]);
      int s1 = __builtin_amdgcn_readfirstlane(csr_send[b0 + j5]);
      int s2 = __builtin_amdgcn_readfirstlane(csr_send[b0 + j6]);
      int s3 = __builtin_amdgcn_readfirstlane(csr_send[b0 + j7]);
      n0 = *(const uint2*)(kv8 + (size_t)s0 * 512 + kvoff);
      n1 = *(const uint2*)(kv8 + (size_t)s1 * 512 + kvoff);
      n2 = *(const uint2*)(kv8 + (size_t)s2 * 512 + kvoff);
      n3 = *(const uint2*)(kv8 + (size_t)s3 * 512 + kvoff);
    }
    // compute on current batch
    f32x2 kA0 = __builtin_amdgcn_cvt_pk_f32_fp8(c0.x, false);
    f32x2 kA1 = __builtin_amdgcn_cvt_pk_f32_fp8(c0.x, true);
    f32x2 kB0 = __builtin_amdgcn_cvt_pk_f32_fp8(c1.x, false);
    f32x2 kB1 = __builtin_amdgcn_cvt_pk_f32_fp8(c1.x, true);
    f32x2 kC0 = __builtin_amdgcn_cvt_pk_f32_fp8(c2.x, false);
    f32x2 kC1 = __builtin_amdgcn_cvt_pk_f32_fp8(c2.x, true);
    f32x2 kD0 = __builtin_amdgcn_cvt_pk_f32_fp8(c3.x, false);
    f32x2 kD1 = __builtin_amdgcn_cvt_pk_f32_fp8(c3.x, true);
    float p0 = q0 * kA0[0] + q1 * kA0[1] + q2 * kA1[0] + q3 * kA1[1];
    float p1 = q0 * kB0[0] + q1 * kB0[1] + q2 * kB1[0] + q3 * kB1[1];
    float p2 = q0 * kC0[0] + q1 * kC0[1] + q2 * kC1[0] + q3 * kC1[1];
    float p3 = q0 * kD0[0] + q1 * kD0[1] + q2 * kD1[0] + q3 * kD1[1];
    p0 = sum16(p0); p1 = sum16(p1); p2 = sum16(p2); p3 = sum16(p3);
    float e0 = exp2f(p0);
    float e1 = (j + 1 < dn) ? exp2f(p1) : 0.f;
    float e2 = (j + 2 < dn) ? exp2f(p2) : 0.f;
    float e3 = (j + 3 < dn) ? exp2f(p3) : 0.f;
    l += e0 + e1 + e2 + e3;
    f32x2 vA0 = __builtin_amdgcn_cvt_pk_f32_fp8(c0.y, false);
    f32x2 vA1 = __builtin_amdgcn_cvt_pk_f32_fp8(c0.y, true);
    f32x2 vB0 = __builtin_amdgcn_cvt_pk_f32_fp8(c1.y, false);
    f32x2 vB1 = __builtin_amdgcn_cvt_pk_f32_fp8(c1.y, true);
    f32x2 vC0 = __builtin_amdgcn_cvt_pk_f32_fp8(c2.y, false);
    f32x2 vC1 = __builtin_amdgcn_cvt_pk_f32_fp8(c2.y, true);
    f32x2 vD0 = __builtin_amdgcn_cvt_pk_f32_fp8(c3.y, false);
    f32x2 vD1 = __builtin_amdgcn_cvt_pk_f32_fp8(c3.y, true);
    a0 += e0 * vA0[0] + e1 * vB0[0] + e2 * vC0[0] + e3 * vD0[0];
    a1 += e0 * vA0[1] + e1 * vB0[1] + e2 * vC0[1] + e3 * vD0[1];
    a2 += e0 * vA1[0] + e1 * vB1[0] + e2 * vC1[0] + e3 * vD1[0];
    a3 += e0 * vA1[1] + e1 * vB1[1] + e2 * vC1[1] + e3 * vD1[1];
    // rotate
    c0 = n0; c1 = n1; c2 = n2; c3 = n3;
  }
  ushort4 su = *(const ushort4*)(sbuf + (size_t)n * 256 + dbase);
  float rl = 1.f / (l + 1e-16f);
  float y0 = a0 * rl + b2f(su.x), y1 = a1 * rl + b2f(su.y);
  float y2 = a2 * rl + b2f(su.z), y3 = a3 * rl + b2f(su.w);
  float s1 = wave_reduce_sum(y0 + y1 + y2 + y3);
  float s2 = wave_reduce_sum(y0 * y0 + y1 * y1 + y2 * y2 + y3 * y3);
  float mean = s1 * (1.f / 256.f);
  float var = s2 * (1.f / 256.f) - mean * mean;
  float rstd = rsqrtf(var + 1e-5f);
  ushort4 o;
  o.x = f2b((y0 - mean) * rstd * g[dbase + 0] + bb[dbase + 0]);
  o.y = f2b((y1 - mean) * rstd * g[dbase + 1] + bb[dbase + 1]);
  o.z = f2b((y2 - mean) * rstd * g[dbase + 2] + bb[dbase + 2]);
  o.w = f2b((y3 - mean) * rstd * g[dbase + 3] + bb[dbase + 3]);
  *(ushort4*)(qbuf + (size_t)n * 256 + dbase) = o;   // outn over q
}

// ------------- classifier, fully fused: gather + GEMM + relu + dot(w2) ------
__global__ __launch_bounds__(256) void clf_fused(
    const ushort* __restrict__ nodeB, const int* __restrict__ ei,
    const ushort* __restrict__ ec1T, const float* __restrict__ b1,
    const float* __restrict__ w2, const float* __restrict__ b2v,
    float* __restrict__ out, int E)
{
  __shared__ ushort As[64 * 136];
  __shared__ ushort Bs[64 * 136];
  int tid = threadIdx.x;
  int wv = tid >> 6, lane = tid & 63;
  int r16 = lane & 15, g4 = lane >> 4;
  int e0 = blockIdx.x * 64;
  for (int idx = tid; idx < 1024; idx += 256) {
    int r = idx >> 4, c = idx & 15;
    int e = e0 + r; if (e >= E) e = E - 1;
    int node = (c < 8) ? ei[e] : ei[E + e];
    *(short8*)&As[r * 136 + c * 8] =
        *(const short8*)&nodeB[(size_t)node * 64 + (c & 7) * 8];
    *(short8*)&Bs[r * 136 + c * 8] = *(const short8*)&ec1T[r * 128 + c * 8];
  }
  __syncthreads();
  f32x4 acc[4] = {};
  #pragma unroll
  for (int kk = 0; kk < 4; ++kk) {
    short8 a = *(const short8*)&As[(wv * 16 + r16) * 136 + kk * 32 + g4 * 8];
    #pragma unroll
    for (int ct = 0; ct < 4; ++ct) {
      short8 b = *(const short8*)&Bs[(ct * 16 + r16) * 136 + kk * 32 + g4 * 8];
      acc[ct] = __builtin_amdgcn_mfma_f32_16x16x32_bf16(a, b, acc[ct], 0, 0, 0);
    }
  }
  float p0 = 0.f, p1 = 0.f, p2 = 0.f, p3 = 0.f;
  #pragma unroll
  for (int ct = 0; ct < 4; ++ct) {
    int c = ct * 16 + r16;
    float bb1 = b1[c], ww = w2[c];
    p0 += fmaxf(acc[ct][0] + bb1, 0.f) * ww;
    p1 += fmaxf(acc[ct][1] + bb1, 0.f) * ww;
    p2 += fmaxf(acc[ct][2] + bb1, 0.f) * ww;
    p3 += fmaxf(acc[ct][3] + bb1, 0.f) * ww;
  }
  float part[4] = {p0, p1, p2, p3};
  #pragma unroll
  for (int j = 0; j < 4; ++j) {
    float p = sum16(part[j]);
    int r = e0 + wv * 16 + g4 * 4 + j;
    if (r16 == 0 && r < E) out[r] = p + b2v[0];
  }
}

extern "C" void kernel_launch(void* const* d_in, const int* in_sizes, int n_in,
                              void* d_out, int out_size, void* d_ws, size_t ws_size,
                              hipStream_t stream)
{
  const float* x     = (const float*)d_in[0];
  const float* ea    = (const float*)d_in[1];
  const float* ne_w1 = (const float*)d_in[2];
  const float* ne_b1 = (const float*)d_in[3];
  const float* ne_w2 = (const float*)d_in[4];
  const float* ne_b2 = (const float*)d_in[5];
  const float* ee_w1 = (const float*)d_in[6];
  const float* ee_b1 = (const float*)d_in[7];
  const float* ee_w2 = (const float*)d_in[8];
  const float* ee_b2 = (const float*)d_in[9];
  const float* lnc_g = (const float*)d_in[10];
  const float* lnc_b = (const float*)d_in[11];
  const float* tq_w  = (const float*)d_in[12];
  const float* tq_b  = (const float*)d_in[13];
  const float* tk_w  = (const float*)d_in[14];
  const float* tk_b  = (const float*)d_in[15];
  const float* tv_w  = (const float*)d_in[16];
  const float* tv_b  = (const float*)d_in[17];
  const float* ts_w  = (const float*)d_in[18];
  const float* ts_b  = (const float*)d_in[19];
  const float* lnt_g = (const float*)d_in[20];
  const float* lnt_b = (const float*)d_in[21];
  const float* pn_w  = (const float*)d_in[22];
  const float* pn_b  = (const float*)d_in[23];
  // d_in[24], d_in[25] = pe_w, pe_b : dead code (n_iterations=1)
  const float* ec_w1 = (const float*)d_in[26];
  const float* ec_b1 = (const float*)d_in[27];
  const float* ec_w2 = (const float*)d_in[28];
  const float* ec_b2 = (const float*)d_in[29];
  const int*   ei    = (const int*)d_in[30];

  const int N = in_sizes[0] / 6;
  const int E = in_sizes[1] / 4;
  float* out = (float*)d_out;

  char* w = (char*)d_ws;
  size_t off = 0;
  auto alloc = [&](size_t bytes) -> char* {
    char* p = w + off;
    off = (off + bytes + 255) & ~(size_t)255;
    return p;
  };
  ushort* node0   = (ushort*)alloc((size_t)N * 64 * 2);     // bf16
  ushort* comb    = (ushort*)alloc((size_t)N * 128 * 2);
  ushort* qbuf    = (ushort*)alloc((size_t)N * 256 * 2);    // q, then outn
  unsigned char* kv8 = (unsigned char*)alloc((size_t)N * 512); // fp8 k|v interleaved
  ushort* sbuf    = (ushort*)alloc((size_t)N * 256 * 2);
  ushort* f_csr   = (ushort*)alloc((size_t)2 * E * 64 * 2); // edge feats, slot order
  ushort* nodeB   = (ushort*)alloc((size_t)N * 64 * 2);
  ushort* wqkvsT  = (ushort*)alloc(1024 * 128 * 2);
  float*  bqkvs   = (float*)alloc(1024 * 4);
  ushort* pnT     = (ushort*)alloc(64 * 256 * 2);
  ushort* ec1T    = (ushort*)alloc(64 * 128 * 2);
  ushort* ee2T    = (ushort*)alloc(64 * 64 * 2);
  int* deg      = (int*)alloc((size_t)N * 4);
  int* base     = (int*)alloc((size_t)N * 4);
  int* fillcur  = (int*)alloc((size_t)N * 4);
  int* csr_send = (int*)alloc((size_t)2 * E * 4);
  int2* slot2   = (int2*)alloc((size_t)E * 8);
  int* cursor   = (int*)alloc(256);

  hipMemsetAsync(deg, 0, (size_t)N * 4, stream);
  hipMemsetAsync(cursor, 0, 4, stream);

  // weight prep (transpose + bf16 + kv-permute + q-scale) + degree count
  int prep_n = (E > 160768) ? E : 160768;
  prep_weights<<<(prep_n + 255) / 256, 256, 0, stream>>>(
      tq_w, tk_w, tv_w, ts_w, tq_b, tk_b, tv_b, ts_b, pn_w, ec_w1, ee_w2,
      wqkvsT, bqkvs, pnT, ec1T, ee2T, ei, deg, E);
  // node encoder (fp32 compute, bf16 out)
  node_encoder<<<(N + 3) / 4, 256, 0, stream>>>(x, ne_w1, ne_b1, ne_w2, ne_b2, node0, N);
  // CSR ranges -> slot assignment
  alloc_ranges<<<(N + 63) / 64, 64, 0, stream>>>(deg, base, fillcur, cursor, N);
  csr_fill<<<(E + 255) / 256, 256, 0, stream>>>(ei, fillcur, csr_send, slot2, E);
  // edge encoder -> f_csr (scatter to both slots; agg reads become streaming)
  edge_enc<<<(E + 63) / 64, 256, 0, stream>>>(ea, ee_w1, ee_b1, ee2T, ee_b2,
                                              slot2, f_csr, E);
  // agg (contiguous slab) + comb LN -> bf16
  comb_gather_ln<<<(N * 64 + 255) / 256, 256, 0, stream>>>(
      node0, f_csr, base, deg, lnc_g, lnc_b, comb, N);
  // fused QKVS projection: q/s bf16, kv fp8; col tiles split over grid.y
  qkvs_gemm<<<dim3((N + 63) / 64, 4), 256, 0, stream>>>(
      comb, wqkvsT, bqkvs, qbuf, kv8, sbuf, N);
  // attention + skip + LN (outn over qbuf)
  attn_ln2<<<(N * 64 + 255) / 256, 256, 0, stream>>>(
      qbuf, kv8, sbuf, base, deg, csr_send, lnt_g, lnt_b, N);
  // node projection + residual -> nodeB
  mgemm<<<dim3((N + 63) / 64, 1), 256, 0, stream>>>(
      qbuf, 256, N, pnT, pn_b, 256, nodeB, 64, node0, 64, 0);
  // classifier: gather + GEMM + relu + dot(w2) fused
  clf_fused<<<(E + 63) / 64, 256, 0, stream>>>(
      nodeB, ei, ec1T, ec_b1, ec_w2, ec_b2, out, E);
}